// Round 1
// baseline (247.773 us; speedup 1.0000x reference)
//
#include <hip/hip_runtime.h>
#include <math.h>

typedef __attribute__((ext_vector_type(4))) float f32x4;
typedef __attribute__((ext_vector_type(8))) short short8;

#define DI __device__ __forceinline__

static constexpr int Bb = 8;
static constexpr int Nn = 1024;
static constexpr int Dd = 256;
static constexpr int MROWS = Bb * Nn;   // 8192

DI unsigned short f2bf(float f) {
  union { float f; unsigned u; } v; v.f = f;
  unsigned r = v.u + 0x7fffu + ((v.u >> 16) & 1u);
  return (unsigned short)(r >> 16);
}
DI float bf2f(unsigned short h) {
  union { unsigned u; float f; } v; v.u = ((unsigned)h) << 16; return v.f;
}

// ---------------- stats over sequence dim (axis=1) ----------------
// partial: [B][32][2][256]
__global__ void stats_pass1(const float* __restrict__ x, float* __restrict__ partial) {
  int d = threadIdx.x;
  int b = blockIdx.x >> 5;
  int c = blockIdx.x & 31;
  const float* p = x + ((size_t)b * Nn + c * 32) * Dd + d;
  float s = 0.f, ss = 0.f;
  for (int i = 0; i < 32; i++) { float v = p[(size_t)i * Dd]; s += v; ss += v * v; }
  float* o = partial + ((size_t)(b * 32 + c) * 2) * Dd + d;
  o[0] = s; o[Dd] = ss;
}

__global__ void stats_pass2(const float* __restrict__ partial, float* __restrict__ mean,
                            float* __restrict__ rstd) {
  int d = threadIdx.x; int b = blockIdx.x;
  float s = 0.f, ss = 0.f;
  for (int c = 0; c < 32; c++) {
    s  += partial[((size_t)(b * 32 + c) * 2) * Dd + d];
    ss += partial[((size_t)(b * 32 + c) * 2) * Dd + Dd + d];
  }
  float m = s * (1.f / Nn);
  float var = ss * (1.f / Nn) - m * m;
  mean[b * Dd + d] = m;
  rstd[b * Dd + d] = rsqrtf(var + 1e-5f);
}

// ---------------- norm (+pos) + swish -> bf16 ----------------
template<bool POS>
__global__ void norm_swish(const float* __restrict__ x, const float* __restrict__ mean,
                           const float* __restrict__ rstd, const float* __restrict__ gamma,
                           const float* __restrict__ beta, const float* __restrict__ pos,
                           unsigned short* __restrict__ out) {
  size_t idx = ((size_t)blockIdx.x * 256 + threadIdx.x) * 4;
  int d = (int)(idx & (Dd - 1));
  size_t row = idx >> 8;
  int b = (int)(row >> 10);
  int n = (int)(row & (Nn - 1));
  const float4 xv = *(const float4*)(x + idx);
  const float4 gv = *(const float4*)(gamma + d);
  const float4 bv = *(const float4*)(beta + d);
  const float4 mv = *(const float4*)(mean + b * Dd + d);
  const float4 rv = *(const float4*)(rstd + b * Dd + d);
  float v[4]  = {xv.x, xv.y, xv.z, xv.w};
  float g[4]  = {gv.x, gv.y, gv.z, gv.w};
  float be[4] = {bv.x, bv.y, bv.z, bv.w};
  float mm[4] = {mv.x, mv.y, mv.z, mv.w};
  float rr[4] = {rv.x, rv.y, rv.z, rv.w};
  float pp[4] = {0.f, 0.f, 0.f, 0.f};
  if (POS) {
    const float4 pv = *(const float4*)(pos + (size_t)n * Dd + d);
    pp[0] = pv.x; pp[1] = pv.y; pp[2] = pv.z; pp[3] = pv.w;
  }
  ushort4 o;
  unsigned short* op = (unsigned short*)&o;
  #pragma unroll
  for (int j = 0; j < 4; j++) {
    float val = (v[j] - mm[j]) * rr[j] * g[j] + be[j];
    if (POS) val += pp[j];
    float sw = val / (1.f + __expf(-val));
    op[j] = f2bf(sw);
  }
  *(ushort4*)(out + idx) = o;
}

// ---------------- time projection: sig_ts[b][j] = sigmoid((t @ Wt + bt)[256+j]) ----------------
__global__ void time_proj(const float* __restrict__ t, const float* __restrict__ Wt,
                          const float* __restrict__ bt, float* __restrict__ sig_ts) {
  int j = blockIdx.x * 256 + threadIdx.x;   // 0..1023
  int b = blockIdx.y;
  const float* tb = t + b * 256;
  float acc = bt[256 + j];
  for (int k = 0; k < 256; k++) acc += tb[k] * Wt[k * 1280 + 256 + j];
  sig_ts[b * 1024 + j] = 1.f / (1.f + __expf(-acc));
}

// ---------------- weight transpose f32 [R][C] -> bf16 [C][R] ----------------
__global__ void transpose_w(const float* __restrict__ in, unsigned short* __restrict__ out,
                            int R, int C) {
  __shared__ float tile[32][33];
  int c0 = blockIdx.x * 32, r0 = blockIdx.y * 32;
  int tx = threadIdx.x & 31, ty = threadIdx.x >> 5;
  for (int i = ty; i < 32; i += 8)
    tile[i][tx] = in[(size_t)(r0 + i) * C + c0 + tx];
  __syncthreads();
  for (int i = ty; i < 32; i += 8)
    out[(size_t)(c0 + i) * R + r0 + tx] = f2bf(tile[tx][i]);
}

// ---------------- GEMM: C = A(bf16 [M][K]) @ BT(bf16 [N][K])^T + epilogue ----------------
// EPI 0: qkv — col<1024 -> qk buf bf16 [M][1024]; col>=1024 -> vt transposed bf16
// EPI 1: f32 out = acc + bias + res
// EPI 2: ff  — g = (acc+bias)*aux[b][col]; out = swish(g) -> bf16
template<int EPI>
__global__ __launch_bounds__(256, 2) void gemm_bf16(
    const unsigned short* __restrict__ A, const unsigned short* __restrict__ BT,
    const float* __restrict__ bias, const float* __restrict__ res,
    const float* __restrict__ aux, unsigned short* __restrict__ obf,
    float* __restrict__ of, unsigned short* __restrict__ vt, int K, int Ndim) {
  constexpr int LDT = 72;
  __shared__ __align__(16) unsigned short As[128 * LDT];
  __shared__ __align__(16) unsigned short Bs[128 * LDT];
  const int tid = threadIdx.x, lane = tid & 63, wave = tid >> 6;
  const int wr = wave >> 1, wc = wave & 1;
  const int m0 = blockIdx.y * 128, n0 = blockIdx.x * 128;
  const int sr = tid >> 3, sk = (tid & 7) * 8;
  f32x4 acc[4][4] = {};
  for (int k0 = 0; k0 < K; k0 += 64) {
    __syncthreads();
    #pragma unroll
    for (int p = 0; p < 4; p++) {
      int r = p * 32 + sr;
      *(uint4*)&As[r * LDT + sk] = *(const uint4*)&A[(size_t)(m0 + r) * K + k0 + sk];
      *(uint4*)&Bs[r * LDT + sk] = *(const uint4*)&BT[(size_t)(n0 + r) * K + k0 + sk];
    }
    __syncthreads();
    #pragma unroll
    for (int ks = 0; ks < 2; ks++) {
      short8 af[4], bfr[4];
      #pragma unroll
      for (int i = 0; i < 4; i++) {
        af[i]  = *(const short8*)&As[(wr * 64 + i * 16 + (lane & 15)) * LDT + ks * 32 + (lane >> 4) * 8];
        bfr[i] = *(const short8*)&Bs[(wc * 64 + i * 16 + (lane & 15)) * LDT + ks * 32 + (lane >> 4) * 8];
      }
      #pragma unroll
      for (int mi = 0; mi < 4; mi++)
        #pragma unroll
        for (int ni = 0; ni < 4; ni++)
          acc[mi][ni] = __builtin_amdgcn_mfma_f32_16x16x32_bf16(af[mi], bfr[ni], acc[mi][ni], 0, 0, 0);
    }
  }
  const int rbase = m0 + wr * 64 + ((lane >> 4) << 2);
  const int cb = n0 + wc * 64 + (lane & 15);
  #pragma unroll
  for (int mi = 0; mi < 4; mi++) {
    #pragma unroll
    for (int ni = 0; ni < 4; ni++) {
      const int col = cb + ni * 16;
      const float bv = bias[col];
      const int r0_ = rbase + mi * 16;
      if (EPI == 0) {
        if (col < 1024) {
          #pragma unroll
          for (int j = 0; j < 4; j++)
            obf[(size_t)(r0_ + j) * 1024 + col] = f2bf(acc[mi][ni][j] + bv);
        } else {
          const int hh = (col - 1024) >> 8, cc = (col - 1024) & 255;
          const int b_ = r0_ >> 10, nb = r0_ & (Nn - 1);
          ushort4 pk;
          unsigned short* pp = (unsigned short*)&pk;
          #pragma unroll
          for (int j = 0; j < 4; j++) pp[j] = f2bf(acc[mi][ni][j] + bv);
          *(ushort4*)&vt[((size_t)((b_ * 8 + hh) * 256 + cc)) * 1024 + nb] = pk;
        }
      } else if (EPI == 1) {
        #pragma unroll
        for (int j = 0; j < 4; j++) {
          size_t o = (size_t)(r0_ + j) * Ndim + col;
          of[o] = acc[mi][ni][j] + bv + res[o];
        }
      } else {
        const int b_ = r0_ >> 10;
        const float sg = aux[b_ * 1024 + col];
        #pragma unroll
        for (int j = 0; j < 4; j++) {
          float g = (acc[mi][ni][j] + bv) * sg;
          obf[(size_t)(r0_ + j) * Ndim + col] = f2bf(g / (1.f + __expf(-g)));
        }
      }
    }
  }
}

// ---------------- Gaussian-kernel attention ----------------
// qk: bf16 [8192][1024] (q at h*64, k at 512+h*64); vt: bf16 [(b*8+h)][256][1024]
// aout: bf16 [8192][2048] = out[b,n,h*256+c]
__global__ __launch_bounds__(256, 2) void attn_kernel(
    const unsigned short* __restrict__ qk, const unsigned short* __restrict__ vt,
    unsigned short* __restrict__ aout, const float* __restrict__ scale_p) {
  const int bh = blockIdx.x >> 4;
  const int qt = blockIdx.x & 15;
  const int b = bh >> 3, h = bh & 7;
  const int tid = threadIdx.x, lane = tid & 63, wave = tid >> 6;
  const float sc = scale_p[0];
  const float inv_s2 = 1.f / (sc * sc);

  __shared__ __align__(16) unsigned short Qs[64 * 72];
  __shared__ __align__(16) unsigned short Ks[64 * 72];
  __shared__ __align__(16) unsigned short Ps[64 * 72];
  __shared__ __align__(16) unsigned short Vs[4][64 * 72];
  __shared__ float q2s[64], k2s[64];

  const int sr = tid >> 3, skc = (tid & 7) * 8;
  #pragma unroll
  for (int p = 0; p < 2; p++) {
    int r = p * 32 + sr;
    *(uint4*)&Qs[r * 72 + skc] =
        *(const uint4*)&qk[((size_t)(b * 1024 + qt * 64 + r)) * 1024 + h * 64 + skc];
  }
  __syncthreads();
  {
    int row = tid >> 2, seg = tid & 3;
    float s = 0.f;
    int base = row * 72 + seg * 16;
    #pragma unroll
    for (int i = 0; i < 16; i++) { float v = bf2f(Qs[base + i]); s += v * v; }
    s += __shfl_xor(s, 1);
    s += __shfl_xor(s, 2);
    if (seg == 0) q2s[row] = s;
  }
  f32x4 acc[4][4] = {};
  for (int kt = 0; kt < 16; kt++) {
    __syncthreads();
    #pragma unroll
    for (int p = 0; p < 2; p++) {
      int r = p * 32 + sr;
      *(uint4*)&Ks[r * 72 + skc] =
          *(const uint4*)&qk[((size_t)(b * 1024 + kt * 64 + r)) * 1024 + 512 + h * 64 + skc];
    }
    {
      const int cv = lane >> 3, kv8 = (lane & 7) * 8;
      #pragma unroll
      for (int p = 0; p < 8; p++) {
        int c = p * 8 + cv;
        *(uint4*)&Vs[wave][c * 72 + kv8] =
            *(const uint4*)&vt[((size_t)(bh * 256 + wave * 64 + c)) * 1024 + kt * 64 + kv8];
      }
    }
    __syncthreads();
    {
      int row = tid >> 2, seg = tid & 3;
      float s = 0.f;
      int base = row * 72 + seg * 16;
      #pragma unroll
      for (int i = 0; i < 16; i++) { float v = bf2f(Ks[base + i]); s += v * v; }
      s += __shfl_xor(s, 1);
      s += __shfl_xor(s, 2);
      if (seg == 0) k2s[row] = s;
    }
    __syncthreads();
    // S = Q K^T, this wave's 16-row stripe
    f32x4 sa[4] = {};
    #pragma unroll
    for (int ks = 0; ks < 2; ks++) {
      short8 aq = *(const short8*)&Qs[(wave * 16 + (lane & 15)) * 72 + ks * 32 + (lane >> 4) * 8];
      #pragma unroll
      for (int ni = 0; ni < 4; ni++) {
        short8 bk = *(const short8*)&Ks[(ni * 16 + (lane & 15)) * 72 + ks * 32 + (lane >> 4) * 8];
        sa[ni] = __builtin_amdgcn_mfma_f32_16x16x32_bf16(aq, bk, sa[ni], 0, 0, 0);
      }
    }
    const int prow = wave * 16 + ((lane >> 4) << 2);
    #pragma unroll
    for (int ni = 0; ni < 4; ni++) {
      const int pcol = ni * 16 + (lane & 15);
      const float k2v = k2s[pcol];
      #pragma unroll
      for (int j = 0; j < 4; j++) {
        float d2 = q2s[prow + j] + k2v - 2.f * sa[ni][j];
        float pv = __expf(-fmaxf(d2, 0.f) * inv_s2);
        Ps[(prow + j) * 72 + pcol] = f2bf(pv);
      }
    }
    __syncthreads();
    #pragma unroll
    for (int ks = 0; ks < 2; ks++) {
      short8 ap[4], vb[4];
      #pragma unroll
      for (int i = 0; i < 4; i++) {
        ap[i] = *(const short8*)&Ps[(i * 16 + (lane & 15)) * 72 + ks * 32 + (lane >> 4) * 8];
        vb[i] = *(const short8*)&Vs[wave][(i * 16 + (lane & 15)) * 72 + ks * 32 + (lane >> 4) * 8];
      }
      #pragma unroll
      for (int mi = 0; mi < 4; mi++)
        #pragma unroll
        for (int ci = 0; ci < 4; ci++)
          acc[mi][ci] = __builtin_amdgcn_mfma_f32_16x16x32_bf16(ap[mi], vb[ci], acc[mi][ci], 0, 0, 0);
    }
  }
  const int rb = b * 1024 + qt * 64 + ((lane >> 4) << 2);
  const int cbo = h * 256 + wave * 64 + (lane & 15);
  #pragma unroll
  for (int mi = 0; mi < 4; mi++)
    #pragma unroll
    for (int ci = 0; ci < 4; ci++) {
      #pragma unroll
      for (int j = 0; j < 4; j++)
        aout[(size_t)(rb + mi * 16 + j) * 2048 + cbo + ci * 16] = f2bf(acc[mi][ci][j]);
    }
}

extern "C" void kernel_launch(void* const* d_in, const int* in_sizes, int n_in,
                              void* d_out, int out_size, void* d_ws, size_t ws_size,
                              hipStream_t stream) {
  (void)in_sizes; (void)n_in; (void)out_size; (void)ws_size;
  const float* x      = (const float*)d_in[0];
  const float* t      = (const float*)d_in[1];
  const float* gamma  = (const float*)d_in[2];
  const float* beta   = (const float*)d_in[3];
  const float* pos    = (const float*)d_in[4];
  const float* Wqkv   = (const float*)d_in[5];
  const float* bqkv   = (const float*)d_in[6];
  const float* Wm     = (const float*)d_in[7];
  const float* bm     = (const float*)d_in[8];
  const float* Wt     = (const float*)d_in[9];
  const float* bt     = (const float*)d_in[10];
  const float* gamma1 = (const float*)d_in[11];
  const float* beta1  = (const float*)d_in[12];
  const float* Wf1    = (const float*)d_in[13];
  const float* bf1    = (const float*)d_in[14];
  const float* Wf2    = (const float*)d_in[15];
  const float* bf2    = (const float*)d_in[16];
  const float* scale  = (const float*)d_in[17];
  float* out = (float*)d_out;

  char* ws = (char*)d_ws;
  size_t off = 0;
  auto alloc = [&](size_t bytes) -> void* {
    void* p = ws + off;
    off += (bytes + 255) & ~(size_t)255;
    return p;
  };
  unsigned short* qkb   = (unsigned short*)alloc((size_t)8192 * 1024 * 2);
  unsigned short* vt    = (unsigned short*)alloc((size_t)64 * 256 * 1024 * 2);
  unsigned short* aoutb = (unsigned short*)alloc((size_t)8192 * 2048 * 2);
  unsigned short* hbuf  = (unsigned short*)alloc((size_t)8192 * 256 * 2);
  unsigned short* ffbuf = (unsigned short*)alloc((size_t)8192 * 1024 * 2);
  float* x1             = (float*)alloc((size_t)8192 * 256 * 4);
  unsigned short* WqkvT = (unsigned short*)alloc((size_t)3072 * 256 * 2);
  unsigned short* WmT   = (unsigned short*)alloc((size_t)256 * 2048 * 2);
  unsigned short* Wf1T  = (unsigned short*)alloc((size_t)1024 * 256 * 2);
  unsigned short* Wf2T  = (unsigned short*)alloc((size_t)256 * 1024 * 2);
  float* partial = (float*)alloc((size_t)8 * 32 * 2 * 256 * 4);
  float* mean1   = (float*)alloc(8 * 256 * 4);
  float* rstd1   = (float*)alloc(8 * 256 * 4);
  float* mean2   = (float*)alloc(8 * 256 * 4);
  float* rstd2   = (float*)alloc(8 * 256 * 4);
  float* sig_ts  = (float*)alloc(8 * 1024 * 4);

  transpose_w<<<dim3(96, 8),  256, 0, stream>>>(Wqkv, WqkvT, 256, 3072);
  transpose_w<<<dim3(8, 64),  256, 0, stream>>>(Wm,   WmT,   2048, 256);
  transpose_w<<<dim3(32, 8),  256, 0, stream>>>(Wf1,  Wf1T,  256, 1024);
  transpose_w<<<dim3(8, 32),  256, 0, stream>>>(Wf2,  Wf2T,  1024, 256);

  stats_pass1<<<256, 256, 0, stream>>>(x, partial);
  stats_pass2<<<8, 256, 0, stream>>>(partial, mean1, rstd1);
  time_proj<<<dim3(4, 8), 256, 0, stream>>>(t, Wt, bt, sig_ts);
  norm_swish<true><<<2048, 256, 0, stream>>>(x, mean1, rstd1, gamma, beta, pos, hbuf);

  gemm_bf16<0><<<dim3(24, 64), 256, 0, stream>>>(hbuf, WqkvT, bqkv, nullptr, nullptr,
                                                 qkb, nullptr, vt, 256, 3072);
  attn_kernel<<<1024, 256, 0, stream>>>(qkb, vt, aoutb, scale);
  gemm_bf16<1><<<dim3(2, 64), 256, 0, stream>>>(aoutb, WmT, bm, x, nullptr,
                                                nullptr, x1, nullptr, 2048, 256);

  stats_pass1<<<256, 256, 0, stream>>>(x1, partial);
  stats_pass2<<<8, 256, 0, stream>>>(partial, mean2, rstd2);
  norm_swish<false><<<2048, 256, 0, stream>>>(x1, mean2, rstd2, gamma1, beta1, nullptr, hbuf);

  gemm_bf16<2><<<dim3(8, 64), 256, 0, stream>>>(hbuf, Wf1T, bf1, nullptr, sig_ts,
                                                ffbuf, nullptr, nullptr, 256, 1024);
  gemm_bf16<1><<<dim3(2, 64), 256, 0, stream>>>(ffbuf, Wf2T, bf2, x1, nullptr,
                                                nullptr, out, nullptr, 1024, 256);
}

// Round 4
// 212.748 us; speedup vs baseline: 1.1646x; 1.1646x over previous
//
#include <hip/hip_runtime.h>
#include <math.h>

typedef __attribute__((ext_vector_type(4))) float f32x4;
typedef __attribute__((ext_vector_type(16))) float f32x16;
typedef __attribute__((ext_vector_type(8))) short short8;

#define DI __device__ __forceinline__

static constexpr int Bb = 8;
static constexpr int Nn = 1024;
static constexpr int Dd = 256;

DI unsigned short f2bf(float f) {
  union { float f; unsigned u; } v; v.f = f;
  unsigned r = v.u + 0x7fffu + ((v.u >> 16) & 1u);
  return (unsigned short)(r >> 16);
}
DI float bf2f(unsigned short h) {
  union { unsigned u; float f; } v; v.u = ((unsigned)h) << 16; return v.f;
}

DI void gload_lds16(const void* g, void* l) {
  __builtin_amdgcn_global_load_lds((const __attribute__((address_space(1))) unsigned int*)g,
                                   (__attribute__((address_space(3))) unsigned int*)l, 16, 0, 0);
}

// ---------------- stats over sequence dim (axis=1) ----------------
__global__ void stats_pass1(const float* __restrict__ x, float* __restrict__ partial) {
  int d = threadIdx.x;
  int b = blockIdx.x >> 5;
  int c = blockIdx.x & 31;
  const float* p = x + ((size_t)b * Nn + c * 32) * Dd + d;
  float s = 0.f, ss = 0.f;
  for (int i = 0; i < 32; i++) { float v = p[(size_t)i * Dd]; s += v; ss += v * v; }
  float* o = partial + ((size_t)(b * 32 + c) * 2) * Dd + d;
  o[0] = s; o[Dd] = ss;
}

__global__ void stats_pass2(const float* __restrict__ partial, float* __restrict__ mean,
                            float* __restrict__ rstd) {
  int d = threadIdx.x; int b = blockIdx.x;
  float s = 0.f, ss = 0.f;
  for (int c = 0; c < 32; c++) {
    s  += partial[((size_t)(b * 32 + c) * 2) * Dd + d];
    ss += partial[((size_t)(b * 32 + c) * 2) * Dd + Dd + d];
  }
  float m = s * (1.f / Nn);
  float var = ss * (1.f / Nn) - m * m;
  mean[b * Dd + d] = m;
  rstd[b * Dd + d] = rsqrtf(var + 1e-5f);
}

// ---------------- norm (+pos) + swish -> bf16 ----------------
template<bool POS>
__global__ void norm_swish(const float* __restrict__ x, const float* __restrict__ mean,
                           const float* __restrict__ rstd, const float* __restrict__ gamma,
                           const float* __restrict__ beta, const float* __restrict__ pos,
                           unsigned short* __restrict__ out) {
  size_t idx = ((size_t)blockIdx.x * 256 + threadIdx.x) * 4;
  int d = (int)(idx & (Dd - 1));
  size_t row = idx >> 8;
  int b = (int)(row >> 10);
  int n = (int)(row & (Nn - 1));
  const float4 xv = *(const float4*)(x + idx);
  const float4 gv = *(const float4*)(gamma + d);
  const float4 bv = *(const float4*)(beta + d);
  const float4 mv = *(const float4*)(mean + b * Dd + d);
  const float4 rv = *(const float4*)(rstd + b * Dd + d);
  float v[4]  = {xv.x, xv.y, xv.z, xv.w};
  float g[4]  = {gv.x, gv.y, gv.z, gv.w};
  float be[4] = {bv.x, bv.y, bv.z, bv.w};
  float mm[4] = {mv.x, mv.y, mv.z, mv.w};
  float rr[4] = {rv.x, rv.y, rv.z, rv.w};
  float pp[4] = {0.f, 0.f, 0.f, 0.f};
  if (POS) {
    const float4 pv = *(const float4*)(pos + (size_t)n * Dd + d);
    pp[0] = pv.x; pp[1] = pv.y; pp[2] = pv.z; pp[3] = pv.w;
  }
  ushort4 o;
  unsigned short* op = (unsigned short*)&o;
  #pragma unroll
  for (int j = 0; j < 4; j++) {
    float val = (v[j] - mm[j]) * rr[j] * g[j] + be[j];
    if (POS) val += pp[j];
    float sw = val / (1.f + __expf(-val));
    op[j] = f2bf(sw);
  }
  *(ushort4*)(out + idx) = o;
}

// ---------------- time projection ----------------
__global__ void time_proj(const float* __restrict__ t, const float* __restrict__ Wt,
                          const float* __restrict__ bt, float* __restrict__ sig_ts) {
  int j = blockIdx.x * 256 + threadIdx.x;
  int b = blockIdx.y;
  const float* tb = t + b * 256;
  float acc = bt[256 + j];
  for (int k = 0; k < 256; k++) acc += tb[k] * Wt[k * 1280 + 256 + j];
  sig_ts[b * 1024 + j] = 1.f / (1.f + __expf(-acc));
}

// ---------------- weight transpose f32 [R][C] -> bf16 [C][R] ----------------
__global__ void transpose_w(const float* __restrict__ in, unsigned short* __restrict__ out,
                            int R, int C) {
  __shared__ float tile[32][33];
  int c0 = blockIdx.x * 32, r0 = blockIdx.y * 32;
  int tx = threadIdx.x & 31, ty = threadIdx.x >> 5;
  for (int i = ty; i < 32; i += 8)
    tile[i][tx] = in[(size_t)(r0 + i) * C + c0 + tx];
  __syncthreads();
  for (int i = ty; i < 32; i += 8)
    out[(size_t)(c0 + i) * R + r0 + tx] = f2bf(tile[tx][i]);
}

// ---------------- GEMM (m97-style: linear LDS + global_load_lds) ----------------
// EPI 0: qkv split epilogue; EPI 1: f32 out = acc+bias+res; EPI 2: gated swish -> bf16
template<int EPI, int BN>
__global__ __launch_bounds__(256, 3) void gemm2(
    const unsigned short* __restrict__ A, const unsigned short* __restrict__ BT,
    const float* __restrict__ bias, const float* __restrict__ res,
    const float* __restrict__ aux, unsigned short* __restrict__ obf,
    float* __restrict__ of, unsigned short* __restrict__ vtb, int K, int Ndim) {
  __shared__ __align__(16) unsigned short As[128 * 64];
  __shared__ __align__(16) unsigned short Bs[BN * 64];
  const int tid = threadIdx.x, lane = tid & 63, wave = tid >> 6;
  const int wr = wave >> 1, wc = wave & 1;
  constexpr int NI = (BN == 128) ? 4 : 2;
  constexpr int WCW = (BN == 128) ? 64 : 32;
  const int m0 = blockIdx.y * 128, n0 = blockIdx.x * BN;
  f32x4 acc[4][NI] = {};
  for (int k0 = 0; k0 < K; k0 += 64) {
    __syncthreads();
    #pragma unroll
    for (int p = 0; p < 4; p++) {
      const int o = p * 4096 + tid * 16;
      const int row = o >> 7, c8 = (o >> 4) & 7;
      gload_lds16(A + (size_t)(m0 + row) * K + k0 + c8 * 8, (char*)As + o);
    }
    #pragma unroll
    for (int p = 0; p < BN / 32; p++) {
      const int o = p * 4096 + tid * 16;
      const int row = o >> 7, c8 = (o >> 4) & 7;
      gload_lds16(BT + (size_t)(n0 + row) * K + k0 + c8 * 8, (char*)Bs + o);
    }
    __syncthreads();
    #pragma unroll
    for (int ks = 0; ks < 2; ks++) {
      short8 af[4], bfr[NI];
      #pragma unroll
      for (int i = 0; i < 4; i++)
        af[i] = *(const short8*)&As[(wr * 64 + i * 16 + (lane & 15)) * 64 + ks * 32 + (lane >> 4) * 8];
      #pragma unroll
      for (int i = 0; i < NI; i++)
        bfr[i] = *(const short8*)&Bs[(wc * WCW + i * 16 + (lane & 15)) * 64 + ks * 32 + (lane >> 4) * 8];
      #pragma unroll
      for (int mi = 0; mi < 4; mi++)
        #pragma unroll
        for (int ni = 0; ni < NI; ni++)
          acc[mi][ni] = __builtin_amdgcn_mfma_f32_16x16x32_bf16(af[mi], bfr[ni], acc[mi][ni], 0, 0, 0);
    }
  }
  const int rbase = m0 + wr * 64 + ((lane >> 4) << 2);
  const int cb = n0 + wc * WCW + (lane & 15);
  #pragma unroll
  for (int mi = 0; mi < 4; mi++) {
    #pragma unroll
    for (int ni = 0; ni < NI; ni++) {
      const int col = cb + ni * 16;
      const float bv = bias[col];
      const int r0_ = rbase + mi * 16;
      if (EPI == 0) {
        if (col < 1024) {
          #pragma unroll
          for (int j = 0; j < 4; j++)
            obf[(size_t)(r0_ + j) * 1024 + col] = f2bf(acc[mi][ni][j] + bv);
        } else {
          const int hh = (col - 1024) >> 8, cc = (col - 1024) & 255;
          const int b_ = r0_ >> 10, nb = r0_ & (Nn - 1);
          ushort4 pk;
          unsigned short* pp = (unsigned short*)&pk;
          #pragma unroll
          for (int j = 0; j < 4; j++) pp[j] = f2bf(acc[mi][ni][j] + bv);
          *(ushort4*)&vtb[((size_t)((b_ * 8 + hh) * 256 + cc)) * 1024 + nb] = pk;
        }
      } else if (EPI == 1) {
        #pragma unroll
        for (int j = 0; j < 4; j++) {
          size_t o = (size_t)(r0_ + j) * Ndim + col;
          of[o] = acc[mi][ni][j] + bv + res[o];
        }
      } else {
        const int b_ = r0_ >> 10;
        const float sg = aux[b_ * 1024 + col];
        #pragma unroll
        for (int j = 0; j < 4; j++) {
          float g = (acc[mi][ni][j] + bv) * sg;
          obf[(size_t)(r0_ + j) * Ndim + col] = f2bf(g / (1.f + __expf(-g)));
        }
      }
    }
  }
}

// ---------------- Gaussian-kernel attention v2 ----------------
// 32x32x16 MFMA, QBLK=256, 8 waves (4 q-groups x 2 c/k-groups), XOR-swizzled LDS,
// global_load_lds double-buffered K/V staging, 2 barriers/iter.
// qk: bf16 [8192][1024]; vt: bf16 [bh][256][1024]; aout: bf16 [8192][2048]
__global__ __launch_bounds__(512, 2) void attn2(
    const unsigned short* __restrict__ qk, const unsigned short* __restrict__ vt,
    unsigned short* __restrict__ aout, const float* __restrict__ scale_p) {
  const int dd = blockIdx.x;
  const int bh = (dd & 7) + ((dd >> 5) << 3);   // 4 q-tiles of one bh -> same XCD
  const int qt = (dd >> 3) & 3;
  const int b = bh >> 3, h = bh & 7;
  const float sc = scale_p[0];
  const float inv_s2 = 1.f / (sc * sc);

  __shared__ __align__(16) unsigned short Ks[2][64 * 64];
  __shared__ __align__(16) unsigned short Vs[2][256 * 64];
  __shared__ __align__(16) unsigned short Ps[256 * 64];
  __shared__ __align__(16) float k2w[8][32];

  const int tid = threadIdx.x, lane = tid & 63, wave = tid >> 6;
  const int qg = wave >> 1, cg = wave & 1;
  const int l31 = lane & 31, lh = lane >> 5;

  auto stage = [&](int kt, int buf) {
    {
      const int row = tid >> 3;
      const int c8 = (tid & 7) ^ (row & 7);
      gload_lds16(qk + (size_t)(b * 1024 + kt * 64 + row) * 1024 + 512 + h * 64 + c8 * 8,
                  (char*)&Ks[buf][0] + tid * 16);
    }
    #pragma unroll
    for (int p = 0; p < 4; p++) {
      const int o = p * 8192 + tid * 16;
      const int row = o >> 7;
      const int c8 = ((o >> 4) & 7) ^ (row & 7);
      gload_lds16(vt + (size_t)(bh * 256 + row) * 1024 + kt * 64 + c8 * 8,
                  (char*)&Vs[buf][0] + o);
    }
  };

  stage(0, 0);

  // Q fragments (B-operand of swapped QK^T) + per-lane q2, direct from global
  short8 qfrag[2][4];
  float q2r[2];
  const unsigned short* qbase = qk + (size_t)(b * 1024 + qt * 256 + qg * 64) * 1024 + h * 64;
  #pragma unroll
  for (int qc = 0; qc < 2; qc++) {
    float s = 0.f;
    #pragma unroll
    for (int ks = 0; ks < 4; ks++) {
      short8 v = *(const short8*)(qbase + (size_t)(qc * 32 + l31) * 1024 + ks * 16 + lh * 8);
      qfrag[qc][ks] = v;
      #pragma unroll
      for (int j = 0; j < 8; j++) { float f = bf2f(((unsigned short*)&v)[j]); s += f * f; }
    }
    s += __shfl_xor(s, 32);
    q2r[qc] = s;
  }

  f32x16 acc[2][4] = {};
  __syncthreads();   // drains prologue stage (vmcnt) for all waves

  for (int kt = 0; kt < 16; kt++) {
    const int cur = kt & 1;
    if (kt < 15) stage(kt + 1, cur ^ 1);   // in flight until next barrier

    // wave-local k2 over this wave's 32-row k-half (no extra barrier)
    {
      const int r = lane >> 1, half = lane & 1;
      const int row = cg * 32 + r;
      float s = 0.f;
      #pragma unroll
      for (int i = 0; i < 4; i++) {
        const int sl = (half * 4 + i) ^ (row & 7);
        short8 v = *(const short8*)((const char*)&Ks[cur][0] + row * 128 + sl * 16);
        #pragma unroll
        for (int j = 0; j < 8; j++) { float f = bf2f(((unsigned short*)&v)[j]); s += f * f; }
      }
      s += __shfl_xor(s, 1);
      if (half == 0) k2w[wave][r] = s;
    }

    // K fragments (A-operand): rows = k-index within this wave's half
    short8 kf[4];
    #pragma unroll
    for (int ks = 0; ks < 4; ks++) {
      const int row = cg * 32 + l31;
      const int sl = (ks * 2 + lh) ^ (row & 7);
      kf[ks] = *(const short8*)((const char*)&Ks[cur][0] + row * 128 + sl * 16);
    }
    float4 k2q[4];
    #pragma unroll
    for (int g = 0; g < 4; g++) k2q[g] = *(const float4*)&k2w[wave][lh * 4 + g * 8];

    // S^T = mfma(K, Q); epilogue packs P (bf16) into swizzled LDS rows
    #pragma unroll
    for (int qc = 0; qc < 2; qc++) {
      f32x16 sacc = {};
      #pragma unroll
      for (int ks = 0; ks < 4; ks++)
        sacc = __builtin_amdgcn_mfma_f32_32x32x16_bf16(kf[ks], qfrag[qc][ks], sacc, 0, 0, 0);
      const int row = qg * 64 + qc * 32 + l31;
      const int rsw = (row & 7) << 4;
      #pragma unroll
      for (int g = 0; g < 4; g++) {
        ushort4 pk;
        #pragma unroll
        for (int j = 0; j < 4; j++) {
          float d2 = q2r[qc] + ((const float*)&k2q[g])[j] - 2.f * sacc[g * 4 + j];
          float pv = __expf(-fmaxf(d2, 0.f) * inv_s2);
          ((unsigned short*)&pk)[j] = f2bf(pv);
        }
        const int kbyte = cg * 64 + g * 16 + lh * 8;
        *(ushort4*)((char*)Ps + row * 128 + (kbyte ^ rsw)) = pk;
      }
    }
    __syncthreads();   // P visible across cg pair; drains stage(kt+1)

    // PV: out += P @ V   (A = P rows q, B = V rows c, k = m)
    #pragma unroll
    for (int ks = 0; ks < 4; ks++) {
      short8 pf[2];
      #pragma unroll
      for (int mi = 0; mi < 2; mi++) {
        const int row = qg * 64 + mi * 32 + l31;
        const int sl = (ks * 2 + lh) ^ (row & 7);
        pf[mi] = *(const short8*)((const char*)Ps + row * 128 + sl * 16);
      }
      #pragma unroll
      for (int ci = 0; ci < 4; ci++) {
        const int vrow = cg * 128 + ci * 32 + l31;
        const int sl = (ks * 2 + lh) ^ (vrow & 7);
        short8 vf = *(const short8*)((const char*)&Vs[cur][0] + vrow * 128 + sl * 16);
        #pragma unroll
        for (int mi = 0; mi < 2; mi++)
          acc[mi][ci] = __builtin_amdgcn_mfma_f32_32x32x16_bf16(pf[mi], vf, acc[mi][ci], 0, 0, 0);
      }
    }
    __syncthreads();   // all reads of buf[cur] & Ps done before next iter's writes
  }

  const size_t row0 = (size_t)(b * 1024 + qt * 256 + qg * 64);
  #pragma unroll
  for (int mi = 0; mi < 2; mi++)
    #pragma unroll
    for (int ci = 0; ci < 4; ci++) {
      #pragma unroll
      for (int r = 0; r < 16; r++) {
        const int q = mi * 32 + (r & 3) + 8 * (r >> 2) + 4 * lh;
        const int c = h * 256 + cg * 128 + ci * 32 + l31;
        aout[(row0 + q) * 2048 + c] = f2bf(acc[mi][ci][r]);
      }
    }
}

extern "C" void kernel_launch(void* const* d_in, const int* in_sizes, int n_in,
                              void* d_out, int out_size, void* d_ws, size_t ws_size,
                              hipStream_t stream) {
  (void)in_sizes; (void)n_in; (void)out_size; (void)ws_size;
  const float* x      = (const float*)d_in[0];
  const float* t      = (const float*)d_in[1];
  const float* gamma  = (const float*)d_in[2];
  const float* beta   = (const float*)d_in[3];
  const float* pos    = (const float*)d_in[4];
  const float* Wqkv   = (const float*)d_in[5];
  const float* bqkv   = (const float*)d_in[6];
  const float* Wm     = (const float*)d_in[7];
  const float* bm     = (const float*)d_in[8];
  const float* Wt     = (const float*)d_in[9];
  const float* bt     = (const float*)d_in[10];
  const float* gamma1 = (const float*)d_in[11];
  const float* beta1  = (const float*)d_in[12];
  const float* Wf1    = (const float*)d_in[13];
  const float* bf1    = (const float*)d_in[14];
  const float* Wf2    = (const float*)d_in[15];
  const float* bf2    = (const float*)d_in[16];
  const float* scale  = (const float*)d_in[17];
  float* out = (float*)d_out;

  char* ws = (char*)d_ws;
  size_t off = 0;
  auto alloc = [&](size_t bytes) -> void* {
    void* p = ws + off;
    off += (bytes + 255) & ~(size_t)255;
    return p;
  };
  unsigned short* qkb   = (unsigned short*)alloc((size_t)8192 * 1024 * 2);
  unsigned short* vtb   = (unsigned short*)alloc((size_t)64 * 256 * 1024 * 2);
  unsigned short* aoutb = (unsigned short*)alloc((size_t)8192 * 2048 * 2);
  unsigned short* hbuf  = (unsigned short*)alloc((size_t)8192 * 256 * 2);
  unsigned short* ffbuf = (unsigned short*)alloc((size_t)8192 * 1024 * 2);
  float* x1             = (float*)alloc((size_t)8192 * 256 * 4);
  unsigned short* WqkvT = (unsigned short*)alloc((size_t)3072 * 256 * 2);
  unsigned short* WmT   = (unsigned short*)alloc((size_t)256 * 2048 * 2);
  unsigned short* Wf1T  = (unsigned short*)alloc((size_t)1024 * 256 * 2);
  unsigned short* Wf2T  = (unsigned short*)alloc((size_t)256 * 1024 * 2);
  float* partial = (float*)alloc((size_t)8 * 32 * 2 * 256 * 4);
  float* mean1   = (float*)alloc(8 * 256 * 4);
  float* rstd1   = (float*)alloc(8 * 256 * 4);
  float* mean2   = (float*)alloc(8 * 256 * 4);
  float* rstd2   = (float*)alloc(8 * 256 * 4);
  float* sig_ts  = (float*)alloc(8 * 1024 * 4);

  transpose_w<<<dim3(96, 8),  256, 0, stream>>>(Wqkv, WqkvT, 256, 3072);
  transpose_w<<<dim3(8, 64),  256, 0, stream>>>(Wm,   WmT,   2048, 256);
  transpose_w<<<dim3(32, 8),  256, 0, stream>>>(Wf1,  Wf1T,  256, 1024);
  transpose_w<<<dim3(8, 32),  256, 0, stream>>>(Wf2,  Wf2T,  1024, 256);

  stats_pass1<<<256, 256, 0, stream>>>(x, partial);
  stats_pass2<<<8, 256, 0, stream>>>(partial, mean1, rstd1);
  time_proj<<<dim3(4, 8), 256, 0, stream>>>(t, Wt, bt, sig_ts);
  norm_swish<true><<<2048, 256, 0, stream>>>(x, mean1, rstd1, gamma, beta, pos, hbuf);

  gemm2<0, 128><<<dim3(24, 64), 256, 0, stream>>>(hbuf, WqkvT, bqkv, nullptr, nullptr,
                                                  qkb, nullptr, vtb, 256, 3072);
  attn2<<<256, 512, 0, stream>>>(qkb, vtb, aoutb, scale);
  gemm2<1, 64><<<dim3(4, 64), 256, 0, stream>>>(aoutb, WmT, bm, x, nullptr,
                                                nullptr, x1, nullptr, 2048, 256);

  stats_pass1<<<256, 256, 0, stream>>>(x1, partial);
  stats_pass2<<<8, 256, 0, stream>>>(partial, mean2, rstd2);
  norm_swish<false><<<2048, 256, 0, stream>>>(x1, mean2, rstd2, gamma1, beta1, nullptr, hbuf);

  gemm2<2, 128><<<dim3(8, 64), 256, 0, stream>>>(hbuf, Wf1T, bf1, nullptr, sig_ts,
                                                 ffbuf, nullptr, nullptr, 256, 1024);
  gemm2<1, 64><<<dim3(4, 64), 256, 0, stream>>>(ffbuf, Wf2T, bf2, x1, nullptr,
                                                nullptr, out, nullptr, 1024, 256);
}

// Round 6
// 206.907 us; speedup vs baseline: 1.1975x; 1.0282x over previous
//
#include <hip/hip_runtime.h>
#include <math.h>

typedef __attribute__((ext_vector_type(4))) float f32x4;
typedef __attribute__((ext_vector_type(16))) float f32x16;
typedef __attribute__((ext_vector_type(8))) short short8;

#define DI __device__ __forceinline__

static constexpr int Bb = 8;
static constexpr int Nn = 1024;
static constexpr int Dd = 256;

DI unsigned short f2bf(float f) {
  union { float f; unsigned u; } v; v.f = f;
  unsigned r = v.u + 0x7fffu + ((v.u >> 16) & 1u);
  return (unsigned short)(r >> 16);
}
DI float bf2f(unsigned short h) {
  union { unsigned u; float f; } v; v.u = ((unsigned)h) << 16; return v.f;
}

DI void gload_lds16(const void* g, void* l) {
  __builtin_amdgcn_global_load_lds((const __attribute__((address_space(1))) unsigned int*)g,
                                   (__attribute__((address_space(3))) unsigned int*)l, 16, 0, 0);
}

// ---------------- stats over sequence dim (axis=1) ----------------
__global__ void stats_pass1(const float* __restrict__ x, float* __restrict__ partial) {
  int d = threadIdx.x;
  int b = blockIdx.x >> 5;
  int c = blockIdx.x & 31;
  const float* p = x + ((size_t)b * Nn + c * 32) * Dd + d;
  float s = 0.f, ss = 0.f;
  for (int i = 0; i < 32; i++) { float v = p[(size_t)i * Dd]; s += v; ss += v * v; }
  float* o = partial + ((size_t)(b * 32 + c) * 2) * Dd + d;
  o[0] = s; o[Dd] = ss;
}

__global__ void stats_pass2(const float* __restrict__ partial, float* __restrict__ mean,
                            float* __restrict__ rstd) {
  int d = threadIdx.x; int b = blockIdx.x;
  float s = 0.f, ss = 0.f;
  for (int c = 0; c < 32; c++) {
    s  += partial[((size_t)(b * 32 + c) * 2) * Dd + d];
    ss += partial[((size_t)(b * 32 + c) * 2) * Dd + Dd + d];
  }
  float m = s * (1.f / Nn);
  float var = ss * (1.f / Nn) - m * m;
  mean[b * Dd + d] = m;
  rstd[b * Dd + d] = rsqrtf(var + 1e-5f);
}

// ---------------- norm (+pos) + swish -> bf16 ----------------
template<bool POS>
__global__ void norm_swish(const float* __restrict__ x, const float* __restrict__ mean,
                           const float* __restrict__ rstd, const float* __restrict__ gamma,
                           const float* __restrict__ beta, const float* __restrict__ pos,
                           unsigned short* __restrict__ out) {
  size_t idx = ((size_t)blockIdx.x * 256 + threadIdx.x) * 4;
  int d = (int)(idx & (Dd - 1));
  size_t row = idx >> 8;
  int b = (int)(row >> 10);
  int n = (int)(row & (Nn - 1));
  const float4 xv = *(const float4*)(x + idx);
  const float4 gv = *(const float4*)(gamma + d);
  const float4 bv = *(const float4*)(beta + d);
  const float4 mv = *(const float4*)(mean + b * Dd + d);
  const float4 rv = *(const float4*)(rstd + b * Dd + d);
  float v[4]  = {xv.x, xv.y, xv.z, xv.w};
  float g[4]  = {gv.x, gv.y, gv.z, gv.w};
  float be[4] = {bv.x, bv.y, bv.z, bv.w};
  float mm[4] = {mv.x, mv.y, mv.z, mv.w};
  float rr[4] = {rv.x, rv.y, rv.z, rv.w};
  float pp[4] = {0.f, 0.f, 0.f, 0.f};
  if (POS) {
    const float4 pv = *(const float4*)(pos + (size_t)n * Dd + d);
    pp[0] = pv.x; pp[1] = pv.y; pp[2] = pv.z; pp[3] = pv.w;
  }
  ushort4 o;
  unsigned short* op = (unsigned short*)&o;
  #pragma unroll
  for (int j = 0; j < 4; j++) {
    float val = (v[j] - mm[j]) * rr[j] * g[j] + be[j];
    if (POS) val += pp[j];
    float sw = val / (1.f + __expf(-val));
    op[j] = f2bf(sw);
  }
  *(ushort4*)(out + idx) = o;
}

// ---------------- time projection ----------------
__global__ void time_proj(const float* __restrict__ t, const float* __restrict__ Wt,
                          const float* __restrict__ bt, float* __restrict__ sig_ts) {
  int j = blockIdx.x * 256 + threadIdx.x;
  int b = blockIdx.y;
  const float* tb = t + b * 256;
  float acc = bt[256 + j];
  for (int k = 0; k < 256; k++) acc += tb[k] * Wt[k * 1280 + 256 + j];
  sig_ts[b * 1024 + j] = 1.f / (1.f + __expf(-acc));
}

// ---------------- weight transpose f32 [R][C] -> bf16 [C][R] ----------------
__global__ void transpose_w(const float* __restrict__ in, unsigned short* __restrict__ out,
                            int R, int C) {
  __shared__ float tile[32][33];
  int c0 = blockIdx.x * 32, r0 = blockIdx.y * 32;
  int tx = threadIdx.x & 31, ty = threadIdx.x >> 5;
  for (int i = ty; i < 32; i += 8)
    tile[i][tx] = in[(size_t)(r0 + i) * C + c0 + tx];
  __syncthreads();
  for (int i = ty; i < 32; i += 8)
    out[(size_t)(c0 + i) * R + r0 + tx] = f2bf(tile[tx][i]);
}

// ---------------- q2/k2 precompute from qk buffer ----------------
// qk: bf16 [8192][1024]; q2,k2: f32 [64][1024] (bh-major)
__global__ void q2k2_kernel(const unsigned short* __restrict__ qk,
                            float* __restrict__ q2, float* __restrict__ k2) {
  const int wave = threadIdx.x >> 6, lane = threadIdx.x & 63;
  const int r = blockIdx.x * 4 + wave;   // row 0..8191
  const int b = r >> 10, n = r & 1023;
  short8 v = *(const short8*)(qk + (size_t)r * 1024 + lane * 16);
  float s = 0.f;
  #pragma unroll
  for (int j = 0; j < 8; j++) { float f = bf2f(((unsigned short*)&v)[j]); s += f * f; }
  short8 v2 = *(const short8*)(qk + (size_t)r * 1024 + lane * 16 + 8);
  #pragma unroll
  for (int j = 0; j < 8; j++) { float f = bf2f(((unsigned short*)&v2)[j]); s += f * f; }
  s += __shfl_xor(s, 1);
  s += __shfl_xor(s, 2);
  if ((lane & 3) == 0) {
    const int seg = lane >> 2;                 // 0..15
    float* dst = (seg < 8) ? q2 : k2;
    dst[(size_t)(b * 8 + (seg & 7)) * 1024 + n] = s;
  }
}

// ---------------- GEMM (m97-style: linear LDS + global_load_lds) ----------------
// EPI 0: qkv split epilogue; EPI 1: f32 out = acc+bias+res; EPI 2: gated swish -> bf16
template<int EPI, int BN>
__global__ __launch_bounds__(256, 3) void gemm2(
    const unsigned short* __restrict__ A, const unsigned short* __restrict__ BT,
    const float* __restrict__ bias, const float* __restrict__ res,
    const float* __restrict__ aux, unsigned short* __restrict__ obf,
    float* __restrict__ of, unsigned short* __restrict__ vtb, int K, int Ndim) {
  __shared__ __align__(16) unsigned short As[128 * 64];
  __shared__ __align__(16) unsigned short Bs[BN * 64];
  const int tid = threadIdx.x, lane = tid & 63, wave = tid >> 6;
  const int wr = wave >> 1, wc = wave & 1;
  constexpr int NI = (BN == 128) ? 4 : 2;
  constexpr int WCW = (BN == 128) ? 64 : 32;
  const int m0 = blockIdx.y * 128, n0 = blockIdx.x * BN;
  f32x4 acc[4][NI] = {};
  for (int k0 = 0; k0 < K; k0 += 64) {
    __syncthreads();
    #pragma unroll
    for (int p = 0; p < 4; p++) {
      const int o = p * 4096 + tid * 16;
      const int row = o >> 7, c8 = (o >> 4) & 7;
      gload_lds16(A + (size_t)(m0 + row) * K + k0 + c8 * 8, (char*)As + o);
    }
    #pragma unroll
    for (int p = 0; p < BN / 32; p++) {
      const int o = p * 4096 + tid * 16;
      const int row = o >> 7, c8 = (o >> 4) & 7;
      gload_lds16(BT + (size_t)(n0 + row) * K + k0 + c8 * 8, (char*)Bs + o);
    }
    __syncthreads();
    #pragma unroll
    for (int ks = 0; ks < 2; ks++) {
      short8 af[4], bfr[NI];
      #pragma unroll
      for (int i = 0; i < 4; i++)
        af[i] = *(const short8*)&As[(wr * 64 + i * 16 + (lane & 15)) * 64 + ks * 32 + (lane >> 4) * 8];
      #pragma unroll
      for (int i = 0; i < NI; i++)
        bfr[i] = *(const short8*)&Bs[(wc * WCW + i * 16 + (lane & 15)) * 64 + ks * 32 + (lane >> 4) * 8];
      #pragma unroll
      for (int mi = 0; mi < 4; mi++)
        #pragma unroll
        for (int ni = 0; ni < NI; ni++)
          acc[mi][ni] = __builtin_amdgcn_mfma_f32_16x16x32_bf16(af[mi], bfr[ni], acc[mi][ni], 0, 0, 0);
    }
  }
  const int rbase = m0 + wr * 64 + ((lane >> 4) << 2);
  const int cb = n0 + wc * WCW + (lane & 15);
  #pragma unroll
  for (int mi = 0; mi < 4; mi++) {
    #pragma unroll
    for (int ni = 0; ni < NI; ni++) {
      const int col = cb + ni * 16;
      const float bv = bias[col];
      const int r0_ = rbase + mi * 16;
      if (EPI == 0) {
        if (col < 1024) {
          #pragma unroll
          for (int j = 0; j < 4; j++)
            obf[(size_t)(r0_ + j) * 1024 + col] = f2bf(acc[mi][ni][j] + bv);
        } else {
          const int hh = (col - 1024) >> 8, cc = (col - 1024) & 255;
          const int b_ = r0_ >> 10, nb = r0_ & (Nn - 1);
          ushort4 pk;
          unsigned short* pp = (unsigned short*)&pk;
          #pragma unroll
          for (int j = 0; j < 4; j++) pp[j] = f2bf(acc[mi][ni][j] + bv);
          *(ushort4*)&vtb[((size_t)((b_ * 8 + hh) * 256 + cc)) * 1024 + nb] = pk;
        }
      } else if (EPI == 1) {
        #pragma unroll
        for (int j = 0; j < 4; j++) {
          size_t o = (size_t)(r0_ + j) * Ndim + col;
          of[o] = acc[mi][ni][j] + bv + res[o];
        }
      } else {
        const int b_ = r0_ >> 10;
        const float sg = aux[b_ * 1024 + col];
        #pragma unroll
        for (int j = 0; j < 4; j++) {
          float g = (acc[mi][ni][j] + bv) * sg;
          obf[(size_t)(r0_ + j) * Ndim + col] = f2bf(g / (1.f + __expf(-g)));
        }
      }
    }
  }
}

// ---------------- Gaussian-kernel attention v3 ----------------
// 8 waves x 32 q-rows each; P stays in registers (cvt_pk + permlane32_swap);
// q2/k2 precomputed; 1 barrier/iter; K/V double-buffered via global_load_lds.
// qk: bf16 [8192][1024]; vt: bf16 [bh][256][1024]; q2g/k2g: f32 [64][1024]
__global__ __launch_bounds__(512, 2) void attn3(
    const unsigned short* __restrict__ qk, const unsigned short* __restrict__ vt,
    const float* __restrict__ q2g, const float* __restrict__ k2g,
    unsigned short* __restrict__ aout, const float* __restrict__ scale_p) {
  const int dd = blockIdx.x;
  const int bh = (dd & 7) + ((dd >> 5) << 3);   // 4 q-tiles of one bh -> same XCD
  const int qt = (dd >> 3) & 3;
  const int b = bh >> 3, h = bh & 7;
  const float sc = scale_p[0];
  const float inv_s2 = 1.f / (sc * sc);

  __shared__ __align__(16) unsigned short Ks[2][64 * 64];
  __shared__ __align__(16) unsigned short Vs[2][256 * 64];

  const int tid = threadIdx.x, lane = tid & 63, wave = tid >> 6;
  const int l31 = lane & 31, lh = lane >> 5;
  const int qr0 = qt * 256 + wave * 32;

  auto stage = [&](int kt, int buf) {
    { // K tile 8 KiB (inverse-swizzled global source, linear LDS dest)
      const int row = tid >> 3;
      const int c8 = (tid & 7) ^ (row & 7);
      gload_lds16(qk + (size_t)(b * 1024 + kt * 64 + row) * 1024 + 512 + h * 64 + c8 * 8,
                  (char*)&Ks[buf][0] + tid * 16);
    }
    #pragma unroll
    for (int p = 0; p < 4; p++) { // V tile 32 KiB
      const int o = p * 8192 + tid * 16;
      const int row = o >> 7;
      const int c8 = ((o >> 4) & 7) ^ (row & 7);
      gload_lds16(vt + (size_t)(bh * 256 + row) * 1024 + kt * 64 + c8 * 8,
                  (char*)&Vs[buf][0] + o);
    }
  };

  stage(0, 0);

  // Q B-frags + q2, direct from global (once per block)
  short8 qfrag[4];
  const unsigned short* qbase = qk + (size_t)(b * 1024 + qr0 + l31) * 1024 + h * 64;
  #pragma unroll
  for (int ks = 0; ks < 4; ks++)
    qfrag[ks] = *(const short8*)(qbase + ks * 16 + lh * 8);
  const float q2v = q2g[(size_t)bh * 1024 + qr0 + l31];

  f32x16 acc[8] = {};
  __syncthreads();   // prologue stage visible

  for (int kt = 0; kt < 16; kt++) {
    const int cur = kt & 1;
    if (kt < 15) stage(kt + 1, cur ^ 1);   // in flight until the barrier

    uint4 pa[4];   // P A-frags, [k-16-slice] x 4 words
    #pragma unroll
    for (int mi = 0; mi < 2; mi++) {
      // S^T = mfma(K, Q): D[k_local][q], k rows mi*32..+31 of this tile
      f32x16 sacc = {};
      #pragma unroll
      for (int ks = 0; ks < 4; ks++) {
        const int row = mi * 32 + l31;
        const int sl = (ks * 2 + lh) ^ (row & 7);
        short8 kf = *(const short8*)((const char*)&Ks[cur][0] + row * 128 + sl * 16);
        sacc = __builtin_amdgcn_mfma_f32_32x32x16_bf16(kf, qfrag[ks], sacc, 0, 0, 0);
      }
      // d2 -> exp, all registers; k2 via broadcast global float4
      const float* k2p = k2g + (size_t)bh * 1024 + kt * 64 + mi * 32 + lh * 4;
      float pr[16];
      #pragma unroll
      for (int g = 0; g < 4; g++) {
        const float4 k2v = *(const float4*)(k2p + g * 8);
        #pragma unroll
        for (int j = 0; j < 4; j++) {
          float d2 = q2v + ((const float*)&k2v)[j] - 2.f * sacc[g * 4 + j];
          pr[g * 4 + j] = __expf(-fmaxf(d2, 0.f) * inv_s2);
        }
      }
      // pack to bf16 A-frags: 8 cvt_pk + 4 permlane32_swap per mi.
      // a=(kslice 4lh+0,4lh+1), b=(+2,+3), c=(8+4lh,+1), d=(8+4lh+2,+3).
      // permlane32_swap(DST,SRC) swaps DST.hi32lanes <-> SRC.lo32lanes:
      //   swap(a,c): a'={a.lo,c.lo}=word0, c'={a.hi,c.hi}=word2
      //   swap(b,d): b'=word1, d'=word3
      #pragma unroll
      for (int ksh = 0; ksh < 2; ksh++) {
        unsigned w0, w1, w2, w3;
        const int o = ksh * 8;
        asm("v_cvt_pk_bf16_f32 %0, %1, %2" : "=v"(w0) : "v"(pr[o + 0]), "v"(pr[o + 1]));
        asm("v_cvt_pk_bf16_f32 %0, %1, %2" : "=v"(w1) : "v"(pr[o + 2]), "v"(pr[o + 3]));
        asm("v_cvt_pk_bf16_f32 %0, %1, %2" : "=v"(w2) : "v"(pr[o + 4]), "v"(pr[o + 5]));
        asm("v_cvt_pk_bf16_f32 %0, %1, %2" : "=v"(w3) : "v"(pr[o + 6]), "v"(pr[o + 7]));
        asm("v_permlane32_swap_b32 %0, %1" : "+v"(w0), "+v"(w2));
        asm("v_permlane32_swap_b32 %0, %1" : "+v"(w1), "+v"(w3));
        pa[mi * 2 + ksh] = make_uint4(w0, w1, w2, w3);
      }
    }
    // PV: acc[ci] += P(32q x 64k) @ V(64k x 256c), V from swizzled LDS
    #pragma unroll
    for (int ci = 0; ci < 8; ci++) {
      #pragma unroll
      for (int ks = 0; ks < 4; ks++) {
        const int row = ci * 32 + l31;
        const int sl = (ks * 2 + lh) ^ (row & 7);
        short8 vf = *(const short8*)((const char*)&Vs[cur][0] + row * 128 + sl * 16);
        short8 paf = *(const short8*)&pa[ks];
        acc[ci] = __builtin_amdgcn_mfma_f32_32x32x16_bf16(paf, vf, acc[ci], 0, 0, 0);
      }
    }
    __syncthreads();   // cur reads done; stage(kt+1) drained (vmcnt0 at barrier)
  }

  const size_t row0 = (size_t)(b * 1024 + qr0);
  #pragma unroll
  for (int ci = 0; ci < 8; ci++) {
    #pragma unroll
    for (int r = 0; r < 16; r++) {
      const int q = (r & 3) + 8 * (r >> 2) + 4 * lh;
      aout[(row0 + q) * 2048 + h * 256 + ci * 32 + l31] = f2bf(acc[ci][r]);
    }
  }
}

extern "C" void kernel_launch(void* const* d_in, const int* in_sizes, int n_in,
                              void* d_out, int out_size, void* d_ws, size_t ws_size,
                              hipStream_t stream) {
  (void)in_sizes; (void)n_in; (void)out_size; (void)ws_size;
  const float* x      = (const float*)d_in[0];
  const float* t      = (const float*)d_in[1];
  const float* gamma  = (const float*)d_in[2];
  const float* beta   = (const float*)d_in[3];
  const float* pos    = (const float*)d_in[4];
  const float* Wqkv   = (const float*)d_in[5];
  const float* bqkv   = (const float*)d_in[6];
  const float* Wm     = (const float*)d_in[7];
  const float* bm     = (const float*)d_in[8];
  const float* Wt     = (const float*)d_in[9];
  const float* bt     = (const float*)d_in[10];
  const float* gamma1 = (const float*)d_in[11];
  const float* beta1  = (const float*)d_in[12];
  const float* Wf1    = (const float*)d_in[13];
  const float* bf1    = (const float*)d_in[14];
  const float* Wf2    = (const float*)d_in[15];
  const float* bf2    = (const float*)d_in[16];
  const float* scale  = (const float*)d_in[17];
  float* out = (float*)d_out;

  char* ws = (char*)d_ws;
  size_t off = 0;
  auto alloc = [&](size_t bytes) -> void* {
    void* p = ws + off;
    off += (bytes + 255) & ~(size_t)255;
    return p;
  };
  unsigned short* qkb   = (unsigned short*)alloc((size_t)8192 * 1024 * 2);
  unsigned short* vtb   = (unsigned short*)alloc((size_t)64 * 256 * 1024 * 2);
  unsigned short* aoutb = (unsigned short*)alloc((size_t)8192 * 2048 * 2);
  unsigned short* hbuf  = (unsigned short*)alloc((size_t)8192 * 256 * 2);
  unsigned short* ffbuf = (unsigned short*)alloc((size_t)8192 * 1024 * 2);
  float* x1             = (float*)alloc((size_t)8192 * 256 * 4);
  unsigned short* WqkvT = (unsigned short*)alloc((size_t)3072 * 256 * 2);
  unsigned short* WmT   = (unsigned short*)alloc((size_t)256 * 2048 * 2);
  unsigned short* Wf1T  = (unsigned short*)alloc((size_t)1024 * 256 * 2);
  unsigned short* Wf2T  = (unsigned short*)alloc((size_t)256 * 1024 * 2);
  float* partial = (float*)alloc((size_t)8 * 32 * 2 * 256 * 4);
  float* mean1   = (float*)alloc(8 * 256 * 4);
  float* rstd1   = (float*)alloc(8 * 256 * 4);
  float* mean2   = (float*)alloc(8 * 256 * 4);
  float* rstd2   = (float*)alloc(8 * 256 * 4);
  float* sig_ts  = (float*)alloc(8 * 1024 * 4);
  float* q2g     = (float*)alloc((size_t)64 * 1024 * 4);
  float* k2g     = (float*)alloc((size_t)64 * 1024 * 4);

  transpose_w<<<dim3(96, 8),  256, 0, stream>>>(Wqkv, WqkvT, 256, 3072);
  transpose_w<<<dim3(8, 64),  256, 0, stream>>>(Wm,   WmT,   2048, 256);
  transpose_w<<<dim3(32, 8),  256, 0, stream>>>(Wf1,  Wf1T,  256, 1024);
  transpose_w<<<dim3(8, 32),  256, 0, stream>>>(Wf2,  Wf2T,  1024, 256);

  stats_pass1<<<256, 256, 0, stream>>>(x, partial);
  stats_pass2<<<8, 256, 0, stream>>>(partial, mean1, rstd1);
  time_proj<<<dim3(4, 8), 256, 0, stream>>>(t, Wt, bt, sig_ts);
  norm_swish<true><<<2048, 256, 0, stream>>>(x, mean1, rstd1, gamma, beta, pos, hbuf);

  gemm2<0, 128><<<dim3(24, 64), 256, 0, stream>>>(hbuf, WqkvT, bqkv, nullptr, nullptr,
                                                  qkb, nullptr, vtb, 256, 3072);
  q2k2_kernel<<<2048, 256, 0, stream>>>(qkb, q2g, k2g);
  attn3<<<256, 512, 0, stream>>>(qkb, vtb, q2g, k2g, aoutb, scale);
  gemm2<1, 64><<<dim3(4, 64), 256, 0, stream>>>(aoutb, WmT, bm, x, nullptr,
                                                nullptr, x1, nullptr, 2048, 256);

  stats_pass1<<<256, 256, 0, stream>>>(x1, partial);
  stats_pass2<<<8, 256, 0, stream>>>(partial, mean2, rstd2);
  norm_swish<false><<<2048, 256, 0, stream>>>(x1, mean2, rstd2, gamma1, beta1, nullptr, hbuf);

  gemm2<2, 128><<<dim3(8, 64), 256, 0, stream>>>(hbuf, Wf1T, bf1, nullptr, sig_ts,
                                                 ffbuf, nullptr, nullptr, 256, 1024);
  gemm2<1, 64><<<dim3(4, 64), 256, 0, stream>>>(ffbuf, Wf2T, bf2, x1, nullptr,
                                                nullptr, out, nullptr, 1024, 256);
}